// Round 1
// baseline (281.904 us; speedup 1.0000x reference)
//
#include <hip/hip_runtime.h>

#define NS 8
#define NC 21
#define HW (512*512)
#define OLD 16
#define IGNORE_IDX 255

// ws layout (bytes)
#define HIST_OFF 0        // int[NS*NC]
#define WGT_OFF  1024     // float[NS*NC]
#define SUM_OFF  2048     // double
#define CNT_OFF  2056     // int
#define WS_BYTES 4096

__device__ __forceinline__ float get4(const float4& v, int j) {
    switch (j) { case 0: return v.x; case 1: return v.y; case 2: return v.z; default: return v.w; }
}

// ---------------- histogram: 64 blocks/sample, 256 thr, 4 int4/thread ----------------
__global__ void __launch_bounds__(256) hist_kernel(const int* __restrict__ tgt,
                                                   int* __restrict__ hist) {
    int n   = blockIdx.x >> 6;
    int blk = blockIdx.x & 63;
    const int4* t4 = reinterpret_cast<const int4*>(tgt + (size_t)n * HW);
    int c0 = 0, c16 = 0, c17 = 0, c18 = 0, c19 = 0, c20 = 0;
#pragma unroll
    for (int it = 0; it < 4; ++it) {
        int idx = blk * 1024 + it * 256 + threadIdx.x;   // HW/4 = 65536 = 64*1024
        int4 t = t4[idx];
#define COUNT_LAB(T) { int lab = (T) < OLD ? 0 : (T);                      \
        c0  += (lab == 0);  c16 += (lab == 16); c17 += (lab == 17);        \
        c18 += (lab == 18); c19 += (lab == 19); c20 += (lab == 20); }
        COUNT_LAB(t.x) COUNT_LAB(t.y) COUNT_LAB(t.z) COUNT_LAB(t.w)
#undef COUNT_LAB
    }
#pragma unroll
    for (int off = 32; off > 0; off >>= 1) {
        c0  += __shfl_down(c0,  off, 64);
        c16 += __shfl_down(c16, off, 64);
        c17 += __shfl_down(c17, off, 64);
        c18 += __shfl_down(c18, off, 64);
        c19 += __shfl_down(c19, off, 64);
        c20 += __shfl_down(c20, off, 64);
    }
    if ((threadIdx.x & 63) == 0) {
        int* h = hist + n * NC;
        atomicAdd(&h[0],  c0);
        atomicAdd(&h[16], c16);
        atomicAdd(&h[17], c17);
        atomicAdd(&h[18], c18);
        atomicAdd(&h[19], c19);
        atomicAdd(&h[20], c20);
    }
}

// ---------------- weights: faithful reproduction of the reference hist logic ----------------
__device__ __forceinline__ float adj_hist(const int* h, int k) {
    if (k >= 1 && k < OLD) return 0.0f;                  // idx_old -> 0
    int raw = h[k];
    if (k == 0) {
        int s = 0;
        for (int j = 0; j < OLD; ++j) s += h[j];         // collapse first 16 into ch 0
        float v = (float)s;
        if (raw == 0) v = 1.0f;                          // idx0 (on raw) & ~idx_old -> 1
        return v;
    }
    return raw == 0 ? 1.0f : (float)raw;
}

__global__ void weight_kernel(const int* __restrict__ hist, float* __restrict__ wgt) {
    int i = threadIdx.x;
    if (i >= NS * NC) return;
    int n = i / NC, c = i % NC;
    const int* h = hist + n * NC;
    float total = 0.0f;
    for (int k = 0; k < NC; ++k) total += adj_hist(h, k);
    float w;
    if (c >= 1 && c < OLD) w = 0.0f;                     // kill infs for old classes
    else                   w = total / adj_hist(h, c);   // RATIO == 1.0
    wgt[i] = w;
}

// ---------------- main loss: 1 thread = 4 pixels, float4 channel loads ----------------
__global__ void __launch_bounds__(256) loss_kernel(const float* __restrict__ in,
                                                   const int* __restrict__ tgt,
                                                   const float* __restrict__ wgt,
                                                   double* __restrict__ sum_acc,
                                                   int* __restrict__ cnt_acc) {
    const int perN = HW / 4;                              // 65536 int4-groups per sample
    int gid = blockIdx.x * 256 + threadIdx.x;
    int n   = gid / perN;
    int p   = (gid - n * perN) * 4;

    // whole block is inside one sample (65536 % 256 == 0): stage weights in LDS
    __shared__ float sw[NC];
    if (threadIdx.x < NC) sw[threadIdx.x] = wgt[n * NC + threadIdx.x];
    __syncthreads();

    const float* base = in + (size_t)n * (NC * HW) + p;
    int4 t = *reinterpret_cast<const int4*>(tgt + (size_t)n * HW + p);

    float4 v[NC];
#pragma unroll
    for (int c = 0; c < NC; ++c)
        v[c] = *reinterpret_cast<const float4*>(base + (size_t)c * HW);

    int labs[4] = {t.x, t.y, t.z, t.w};
    float partial = 0.0f;
    int cnt = 0;
#pragma unroll
    for (int j = 0; j < 4; ++j) {
        int lab = labs[j];
        lab = lab < OLD ? 0 : lab;
        float m16 = -3.4e38f;
#pragma unroll
        for (int c = 0; c < OLD; ++c) m16 = fmaxf(m16, get4(v[c], j));
        float s16 = 0.0f;
#pragma unroll
        for (int c = 0; c < OLD; ++c) s16 += __expf(get4(v[c], j) - m16);
        float m = m16;
#pragma unroll
        for (int c = OLD; c < NC; ++c) m = fmaxf(m, get4(v[c], j));
        float s  = s16 * __expf(m16 - m);
        float xl = 0.0f;
#pragma unroll
        for (int c = OLD; c < NC; ++c) {
            float x = get4(v[c], j);
            s += __expf(x - m);
            xl = (lab == c) ? x : xl;
        }
        float den   = m + __logf(s);
        float lse16 = m16 + __logf(s16);
        float val   = (lab == 0 ? lse16 : xl) - den;
        int  widx   = (lab < NC) ? lab : 0;               // safe index (ignored pixels)
        bool valid  = (lab != IGNORE_IDX);
        if (valid) { partial += sw[widx] * val; cnt++; }
    }

    // wave reduce then cross-wave via LDS
#pragma unroll
    for (int off = 32; off > 0; off >>= 1) {
        partial += __shfl_down(partial, off, 64);
        cnt     += __shfl_down(cnt, off, 64);
    }
    __shared__ float sp[4];
    __shared__ int   sc[4];
    int wave = threadIdx.x >> 6;
    if ((threadIdx.x & 63) == 0) { sp[wave] = partial; sc[wave] = cnt; }
    __syncthreads();
    if (threadIdx.x == 0) {
        float ps = sp[0] + sp[1] + sp[2] + sp[3];
        int   pc = sc[0] + sc[1] + sc[2] + sc[3];
        atomicAdd(sum_acc, (double)ps);
        atomicAdd(cnt_acc, pc);
    }
}

__global__ void finalize_kernel(const double* __restrict__ sum_acc,
                                const int* __restrict__ cnt_acc,
                                float* __restrict__ out) {
    if (threadIdx.x == 0) {
        int c = *cnt_acc;
        out[0] = (c > 0) ? (float)(-(*sum_acc) / (double)c) : 0.0f;
    }
}

extern "C" void kernel_launch(void* const* d_in, const int* in_sizes, int n_in,
                              void* d_out, int out_size, void* d_ws, size_t ws_size,
                              hipStream_t stream) {
    const float* inputs  = (const float*)d_in[0];
    const int*   targets = (const int*)d_in[1];
    float*       out     = (float*)d_out;

    char* ws = (char*)d_ws;
    int*    hist    = (int*)(ws + HIST_OFF);
    float*  wgt     = (float*)(ws + WGT_OFF);
    double* sum_acc = (double*)(ws + SUM_OFF);
    int*    cnt_acc = (int*)(ws + CNT_OFF);

    hipMemsetAsync(d_ws, 0, WS_BYTES, stream);

    hist_kernel<<<NS * 64, 256, 0, stream>>>(targets, hist);
    weight_kernel<<<1, 192, 0, stream>>>(hist, wgt);
    loss_kernel<<<(NS * HW / 4) / 256, 256, 0, stream>>>(inputs, targets, wgt, sum_acc, cnt_acc);
    finalize_kernel<<<1, 64, 0, stream>>>(sum_acc, cnt_acc, out);
}